// Round 10
// baseline (147.169 us; speedup 1.0000x reference)
//
#include <hip/hip_runtime.h>

#define S_LEN 2048
#define B_DIM 32
#define H_DIM 1024
#define ROWS 8       // s-rows per wave in energy kernel (round-4 optimum)
#define KSPLIT 4     // k-split partials in proj (round-4 optimum)
#define KCH (H_DIM / KSPLIT)  // 256

typedef float fx4 __attribute__((ext_vector_type(4)));

// ---------------------------------------------------------------------------
// Kernel 1: vp[kp,b,h] = sum_{k in chunk kp} dec[b,k] * W[k,h]
// EXACT round-4 proj: grid (H/256, B, KSPLIT) = (4, 32, 4) = 512 blocks.
// Block (0,0,0) additionally zeroes the 32 per-row completion counters used
// by the fused softmax (handles the 0xAA ws poison; re-zeroed every call so
// graph replays are deterministic). Kernel boundary on the stream makes the
// zeroes visible to the energy kernel.
// ---------------------------------------------------------------------------
__global__ __launch_bounds__(256) void proj_kernel(
    const float* __restrict__ dec, const float* __restrict__ W,
    float* __restrict__ vp, int* __restrict__ cnt)
{
    if (blockIdx.x == 0 && blockIdx.y == 0 && blockIdx.z == 0 &&
        threadIdx.x < B_DIM)
        cnt[threadIdx.x] = 0;

    const int h  = blockIdx.x * 256 + threadIdx.x;
    const int b  = blockIdx.y;
    const int kp = blockIdx.z;
    const int k0 = kp * KCH;
    const float* __restrict__ drow = dec + (size_t)b * H_DIM;

    float a0 = 0.f, a1 = 0.f, a2 = 0.f, a3 = 0.f;
    for (int kk = 0; kk < KCH; kk += 4) {
        const int k = k0 + kk;
        a0 += drow[k + 0] * W[(size_t)(k + 0) * H_DIM + h];
        a1 += drow[k + 1] * W[(size_t)(k + 1) * H_DIM + h];
        a2 += drow[k + 2] * W[(size_t)(k + 2) * H_DIM + h];
        a3 += drow[k + 3] * W[(size_t)(k + 3) * H_DIM + h];
    }
    vp[((size_t)kp * B_DIM + b) * H_DIM + h] = (a0 + a1) + (a2 + a3);
}

// ---------------------------------------------------------------------------
// Kernel 2: e[b,s] = dot(enc[s,b,:], v[b,:])  + FUSED softmax tail.
// Streaming body is byte-identical to round 4 (60.4 us optimum): grid
// (B/4, S/ROWS) = (8, 256), wave wv owns b = 4x+wv, 8 consecutive s, plain
// float4 loads, two half-groups, 8 interleaved reduce chains.
// Tail: threadFenceReduction pattern. Each block increments cnt[b] for its
// 4 rows; the block seeing old==255 (last of 256 contributors to row b)
// runs the softmax for that row with all 256 threads. Which block finalizes
// varies run-to-run but the computed values do not.
// Bias term c[b] omitted throughout: constant per row, softmax-invariant.
// ---------------------------------------------------------------------------
__global__ __launch_bounds__(256) void energy_kernel(
    const float* __restrict__ enc, const float* __restrict__ vp,
    float* e, int* cnt, float* out)
{
    const int tid  = threadIdx.x;
    const int lane = tid & 63;
    const int wv   = tid >> 6;
    const int b    = blockIdx.x * 4 + wv;
    const int s0   = blockIdx.y * ROWS;

    fx4 vf[4];
#pragma unroll
    for (int i = 0; i < 4; ++i) {
        fx4 t = {0.f, 0.f, 0.f, 0.f};
#pragma unroll
        for (int kp = 0; kp < KSPLIT; ++kp) {
            const fx4* __restrict__ p = reinterpret_cast<const fx4*>(
                vp + ((size_t)kp * B_DIM + b) * H_DIM);
            t += p[lane + 64 * i];
        }
        vf[i] = t;
    }

    float acc[ROWS];
    for (int g = 0; g < 2; ++g) {
        fx4 a[4][4];
#pragma unroll
        for (int r = 0; r < 4; ++r) {
            const fx4* __restrict__ ep = reinterpret_cast<const fx4*>(
                enc + ((size_t)(s0 + g * 4 + r) * B_DIM + b) * H_DIM);
#pragma unroll
            for (int i = 0; i < 4; ++i)
                a[r][i] = ep[lane + 64 * i];
        }
#pragma unroll
        for (int r = 0; r < 4; ++r) {
            float t = 0.f;
#pragma unroll
            for (int i = 0; i < 4; ++i)
                t += a[r][i].x * vf[i].x + a[r][i].y * vf[i].y +
                     a[r][i].z * vf[i].z + a[r][i].w * vf[i].w;
            acc[g * 4 + r] = t;
        }
    }

#pragma unroll
    for (int off = 32; off; off >>= 1) {
#pragma unroll
        for (int r = 0; r < ROWS; ++r)
            acc[r] += __shfl_xor(acc[r], off, 64);
    }

    if (lane == 0) {
        fx4 o0, o1;
        o0.x = acc[0]; o0.y = acc[1]; o0.z = acc[2]; o0.w = acc[3];
        o1.x = acc[4]; o1.y = acc[5]; o1.z = acc[6]; o1.w = acc[7];
        fx4* ep = reinterpret_cast<fx4*>(e + (size_t)b * S_LEN + s0);
        ep[0] = o0;
        ep[1] = o1;
    }

    // ---- fused softmax tail (threadFenceReduction pattern) ----
    __shared__ int olds[4];
    __shared__ float red[4];

    __syncthreads();                       // all 4 waves' e-stores issued
    if (tid < 4) {
        __threadfence();                   // publish e device-wide
        olds[tid] = atomicAdd(&cnt[blockIdx.x * 4 + tid], 1);
    }
    __syncthreads();

    for (int j = 0; j < 4; ++j) {
        if (olds[j] == 255) {              // block-uniform: last for row rb
            const int rb = blockIdx.x * 4 + j;
            __threadfence();               // no stale reads of other blocks' e
            const float* row = e + (size_t)rb * S_LEN;

            float vals[8];
            float m = -1e30f;
#pragma unroll
            for (int i = 0; i < 8; ++i) {
                vals[i] = row[tid + 256 * i];
                m = fmaxf(m, vals[i]);
            }
#pragma unroll
            for (int off = 32; off; off >>= 1)
                m = fmaxf(m, __shfl_xor(m, off, 64));
            if (lane == 0) red[wv] = m;
            __syncthreads();
            m = fmaxf(fmaxf(red[0], red[1]), fmaxf(red[2], red[3]));

            float sum = 0.0f;
#pragma unroll
            for (int i = 0; i < 8; ++i) {
                vals[i] = __expf(vals[i] - m);
                sum += vals[i];
            }
#pragma unroll
            for (int off = 32; off; off >>= 1)
                sum += __shfl_xor(sum, off, 64);
            __syncthreads();               // red reuse hazard
            if (lane == 0) red[wv] = sum;
            __syncthreads();
            sum = red[0] + red[1] + red[2] + red[3];

            const float inv = 1.0f / sum;
#pragma unroll
            for (int i = 0; i < 8; ++i)
                out[(size_t)rb * S_LEN + tid + 256 * i] = vals[i] * inv;
            __syncthreads();               // red safe for next j
        }
    }
}

// ---------------------------------------------------------------------------
extern "C" void kernel_launch(void* const* d_in, const int* in_sizes, int n_in,
                              void* d_out, int out_size, void* d_ws, size_t ws_size,
                              hipStream_t stream)
{
    const float* dec = (const float*)d_in[0];   // [B,H]
    const float* enc = (const float*)d_in[1];   // [S,B,H]
    const float* W   = (const float*)d_in[2];   // [H,H]
    // d_in[3] = bias: constant-per-row contribution, softmax-invariant -> unused
    float* out = (float*)d_out;                 // [B,1,S] flat

    float* vp = (float*)d_ws;                   // KSPLIT*B*H floats (512 KiB)
    float* e  = vp + KSPLIT * B_DIM * H_DIM;    // B*S floats (256 KiB)
    int*   cnt = (int*)(e + B_DIM * S_LEN);     // 32 ints

    proj_kernel<<<dim3(H_DIM / 256, B_DIM, KSPLIT), 256, 0, stream>>>(dec, W, vp, cnt);
    energy_kernel<<<dim3(B_DIM / 4, S_LEN / ROWS), 256, 0, stream>>>(enc, vp, e, cnt, out);
}

// Round 11
// 60.746 us; speedup vs baseline: 2.4227x; 2.4227x over previous
//
#include <hip/hip_runtime.h>

#define S_LEN 2048
#define B_DIM 32
#define H_DIM 1024
#define ROWS 8       // s-rows per wave in energy kernel (measured optimum)
#define KSPLIT 4     // k-split partials in proj (measured optimum)
#define KCH (H_DIM / KSPLIT)  // 256

typedef float fx4 __attribute__((ext_vector_type(4)));

// ---------------------------------------------------------------------------
// Kernel 1: vp[kp,b,h] = sum_{k in chunk kp} dec[b,k] * W[k,h]
// Grid: (H/256, B, KSPLIT) = (4, 32, 4) = 512 blocks x 256 threads.
// W is HBM-cold every replay (the 256 MiB enc stream evicts L3); 512 blocks
// give 2/CU of latency hiding. dec loads thread-uniform -> s_load; W loads
// coalesced. No atomics, no memset: energy sums the partials on load.
// [Round-10 lesson: do NOT fuse softmax into energy — losing __restrict__
//  on e breaks load batching (VGPR 90->56, 3.7x slowdown).]
// ---------------------------------------------------------------------------
__global__ __launch_bounds__(256) void proj_vec_kernel(
    const float* __restrict__ dec, const float* __restrict__ W,
    float* __restrict__ v4)
{
    const int h  = blockIdx.x * 256 + threadIdx.x;
    const int b  = blockIdx.y;
    const int kp = blockIdx.z;
    const int k0 = kp * KCH;
    const float* __restrict__ drow = dec + (size_t)b * H_DIM;

    float a0 = 0.f, a1 = 0.f, a2 = 0.f, a3 = 0.f;
    for (int kk = 0; kk < KCH; kk += 4) {
        const int k = k0 + kk;
        a0 += drow[k + 0] * W[(size_t)(k + 0) * H_DIM + h];
        a1 += drow[k + 1] * W[(size_t)(k + 1) * H_DIM + h];
        a2 += drow[k + 2] * W[(size_t)(k + 2) * H_DIM + h];
        a3 += drow[k + 3] * W[(size_t)(k + 3) * H_DIM + h];
    }
    v4[((size_t)kp * B_DIM + b) * H_DIM + h] = (a0 + a1) + (a2 + a3);
}

// ---------------------------------------------------------------------------
// Kernel 2: e[b,s] = dot(enc[s,b,:], v[b,:]),  v = sum of 4 partials.
// Grid: (B/4, S/ROWS) = (8, 256), x fastest -> 8 consecutive blocks cover a
// full 8-row x 128 KB slab (1 MB) sequentially. Wave wv owns b = 4x+wv and
// 8 consecutive s. v row summed once into 16 VGPRs; enc read via plain
// float4 loads (m13's 6.29 TB/s recipe; nt measured -3.7us, swizzle null),
// 16 loads in flight per half-group, two half-groups to bound VGPR
// pressure, 8 interleaved reduce chains, two fx4 stores.
// ---------------------------------------------------------------------------
__global__ __launch_bounds__(256) void energy_kernel(
    const float* __restrict__ enc, const float* __restrict__ v4,
    float* __restrict__ e)
{
    const int lane = threadIdx.x & 63;
    const int wv   = threadIdx.x >> 6;
    const int b    = blockIdx.x * 4 + wv;
    const int s0   = blockIdx.y * ROWS;

    fx4 vf[4];
#pragma unroll
    for (int i = 0; i < 4; ++i) {
        fx4 t = {0.f, 0.f, 0.f, 0.f};
#pragma unroll
        for (int kp = 0; kp < KSPLIT; ++kp) {
            const fx4* __restrict__ p = reinterpret_cast<const fx4*>(
                v4 + ((size_t)kp * B_DIM + b) * H_DIM);
            t += p[lane + 64 * i];
        }
        vf[i] = t;
    }

    float acc[ROWS];
    for (int g = 0; g < 2; ++g) {
        fx4 a[4][4];
#pragma unroll
        for (int r = 0; r < 4; ++r) {
            const fx4* __restrict__ ep = reinterpret_cast<const fx4*>(
                enc + ((size_t)(s0 + g * 4 + r) * B_DIM + b) * H_DIM);
#pragma unroll
            for (int i = 0; i < 4; ++i)
                a[r][i] = ep[lane + 64 * i];
        }
#pragma unroll
        for (int r = 0; r < 4; ++r) {
            float t = 0.f;
#pragma unroll
            for (int i = 0; i < 4; ++i)
                t += a[r][i].x * vf[i].x + a[r][i].y * vf[i].y +
                     a[r][i].z * vf[i].z + a[r][i].w * vf[i].w;
            acc[g * 4 + r] = t;
        }
    }

#pragma unroll
    for (int off = 32; off; off >>= 1) {
#pragma unroll
        for (int r = 0; r < ROWS; ++r)
            acc[r] += __shfl_xor(acc[r], off, 64);
    }

    if (lane == 0) {
        fx4 o0, o1;
        o0.x = acc[0]; o0.y = acc[1]; o0.z = acc[2]; o0.w = acc[3];
        o1.x = acc[4]; o1.y = acc[5]; o1.z = acc[6]; o1.w = acc[7];
        fx4* ep = reinterpret_cast<fx4*>(e + (size_t)b * S_LEN + s0);
        ep[0] = o0;
        ep[1] = o1;
    }
}

// ---------------------------------------------------------------------------
// Kernel 3: out[b,0,s] = softmax_s(e[b,s]).  One block per b (32 blocks).
// Bias term c[b] omitted: constant per row, softmax-invariant.
// ---------------------------------------------------------------------------
__global__ __launch_bounds__(256) void softmax_kernel(
    const float* __restrict__ e, float* __restrict__ out)
{
    __shared__ float red[4];
    const int b    = blockIdx.x;
    const int tid  = threadIdx.x;
    const int lane = tid & 63;
    const int wv   = tid >> 6;
    const float* __restrict__ row = e + (size_t)b * S_LEN;

    float vals[8];
    float m = -1e30f;
#pragma unroll
    for (int i = 0; i < 8; ++i) {
        vals[i] = row[tid + 256 * i];
        m = fmaxf(m, vals[i]);
    }
#pragma unroll
    for (int off = 32; off; off >>= 1)
        m = fmaxf(m, __shfl_xor(m, off, 64));
    if (lane == 0) red[wv] = m;
    __syncthreads();
    m = fmaxf(fmaxf(red[0], red[1]), fmaxf(red[2], red[3]));

    float sum = 0.0f;
#pragma unroll
    for (int i = 0; i < 8; ++i) {
        vals[i] = __expf(vals[i] - m);
        sum += vals[i];
    }
#pragma unroll
    for (int off = 32; off; off >>= 1)
        sum += __shfl_xor(sum, off, 64);
    __syncthreads();                 // red reuse hazard
    if (lane == 0) red[wv] = sum;
    __syncthreads();
    sum = red[0] + red[1] + red[2] + red[3];

    const float inv = 1.0f / sum;
#pragma unroll
    for (int i = 0; i < 8; ++i)
        out[(size_t)b * S_LEN + tid + 256 * i] = vals[i] * inv;
}

// ---------------------------------------------------------------------------
extern "C" void kernel_launch(void* const* d_in, const int* in_sizes, int n_in,
                              void* d_out, int out_size, void* d_ws, size_t ws_size,
                              hipStream_t stream)
{
    const float* dec = (const float*)d_in[0];   // [B,H]
    const float* enc = (const float*)d_in[1];   // [S,B,H]
    const float* W   = (const float*)d_in[2];   // [H,H]
    // d_in[3] = bias: constant-per-row contribution, softmax-invariant -> unused
    float* out = (float*)d_out;                 // [B,1,S] flat

    float* v4 = (float*)d_ws;                   // KSPLIT*B*H floats (512 KiB)
    float* e  = v4 + KSPLIT * B_DIM * H_DIM;    // B*S floats        (256 KiB)

    proj_vec_kernel<<<dim3(H_DIM / 256, B_DIM, KSPLIT), 256, 0, stream>>>(dec, W, v4);
    energy_kernel<<<dim3(B_DIM / 4, S_LEN / ROWS), 256, 0, stream>>>(enc, v4, e);
    softmax_kernel<<<B_DIM, 256, 0, stream>>>(e, out);
}